// Round 5
// baseline (130.938 us; speedup 1.0000x reference)
//
#include <hip/hip_runtime.h>
#include <math.h>

// (B,P,V,F,H) = (32,512,32,16,64). Round 9: kill correlated stalls.
// Three falsified theories (occupancy v6, spill v6/v5, VMEM volume v8) +
// pipes at ~50% idle at ANY occupancy => stalls are CORRELATED across waves
// (all waves wait on the same thing at the same time). Two candidates this
// version eliminates BOTH of:
//  1. WF mid-chain load latency: all waves hit layerK together, wait on the
//     same 36 KB of W-frags through a thrashing 32-KB L1. Fix: stage WF into
//     LDS once per block (global_load_lds, one barrier); layerK W-reads are
//     conflict-free ds_read_b128 with fixed ~120cy latency, L1 freed for X.
//  2. I$ streaming: fully-unrolled ~40 KB straight-line code > 32 KB L1I,
//     every wave streams it once, fetch stalls hit all waves identically.
//     Fix: real loops — rounds {epi,epi,layerK} x2 and layerK's ks x4 are
//     #pragma unroll 1 (acc only ever statically indexed -> no scratch).
//     ~7 KB of code, I$-resident.
// Also: prep pass packs per-bp u32 masks (1 dword vs 2x int4 + 8 cmp/or)
// and transposed biases (1 dwordx4/layer vs 4 loads).
// Keeps: 2 bp/wave, addm[]=0/-inf pool masking, cvt_pk bf16 packing, no
// per-element out-mask (output = pools only; pools exclude masked rows).
// MFMA 16x16x32 bf16: A[m=lane&15][k=quad*8+j], B[k=quad*8+j][n=lane&15],
//                     D[row=quad*4+reg][col=lane&15]  (verified rounds 2-4).
namespace {
constexpr int kXS = 72;
constexpr float kSlope = 0.01f;

typedef short bf16x8 __attribute__((ext_vector_type(8)));
typedef float f32x4  __attribute__((ext_vector_type(4)));

__device__ __forceinline__ float lrelu(float x) { return fmaxf(x, kSlope * x); }

// 3-instruction round-to-nearest-even f32->bf16 (prep kernel only).
__device__ __forceinline__ unsigned short bfrne(float a) {
    union { float f; unsigned u; } v; v.f = a;
    return (unsigned short)((v.u + 0x7FFFu + ((v.u >> 16) & 1u)) >> 16);
}

// packed 2x f32 -> 2x bf16 (RNE), single VALU op.
__device__ __forceinline__ unsigned cvtpk(float lo, float hi) {
    unsigned r;
    asm("v_cvt_pk_bf16_f32 %0, %1, %2" : "=v"(r) : "v"(lo), "v"(hi));
    return r;
}

// ---- ws layout (bytes): [0,36864) W frags bf16; [36864,37632) biasT f32
//      (biasT[layer][c][nt] = B_layer[nt*16+c]); [37632,103168) u32 masks.
// W frag f: 0..3 = W1 (nt=f, K=16 zero-padded); 4..19 = W2 (nt=(f-4)>>2,
// ks=(f-4)&3); 20..35 = W3. Lane l of frag f at wsW[f*512 + l*8 ..+7].
__global__ void prep_pack(const float* __restrict__ W1,
                          const float* __restrict__ W2,
                          const float* __restrict__ W3,
                          const float* __restrict__ B1,
                          const float* __restrict__ B2,
                          const float* __restrict__ B3,
                          const int* __restrict__ M,
                          unsigned short* __restrict__ wsW,
                          float* __restrict__ wsB,
                          unsigned* __restrict__ wsM)
{
    int t = blockIdx.x * blockDim.x + threadIdx.x;
    if (t < 36 * 64) {
        int f = t >> 6, l = t & 63, c = l & 15, q = l >> 4;
        unsigned short v[8] = {0, 0, 0, 0, 0, 0, 0, 0};
        const float* src = nullptr; int row = 0, k0 = 0, K = 0;
        if (f < 4) {
            if (q < 2) { src = W1; row = 16 * f + c; k0 = q * 8; K = 16; }
        } else if (f < 20) {
            int g = f - 4;  src = W2; row = 16 * (g >> 2) + c; k0 = (g & 3) * 32 + q * 8; K = 128;
        } else {
            int g = f - 20; src = W3; row = 16 * (g >> 2) + c; k0 = (g & 3) * 32 + q * 8; K = 128;
        }
        if (src) {
            #pragma unroll
            for (int j = 0; j < 8; ++j) v[j] = bfrne(src[row * K + k0 + j]);
        }
        unsigned short* dst = wsW + (size_t)f * 512 + l * 8;
        *(ushort4*)(dst)     = make_ushort4(v[0], v[1], v[2], v[3]);
        *(ushort4*)(dst + 4) = make_ushort4(v[4], v[5], v[6], v[7]);
    } else if (t < 36 * 64 + 192) {
        int i = t - 36 * 64; int layer = i >> 6, j = i & 63;
        const float* B = (layer == 0) ? B1 : (layer == 1) ? B2 : B3;
        wsB[layer * 64 + (j & 15) * 4 + (j >> 4)] = B[j];
    } else if (t < 36 * 64 + 192 + 16384) {
        int bp = t - (36 * 64 + 192);
        const int4* mp = (const int4*)(M + bp * 32);
        unsigned bits = 0;
        #pragma unroll
        for (int i = 0; i < 8; ++i) {
            int4 v = mp[i];
            unsigned b = (v.x ? 1u : 0u) | (v.y ? 2u : 0u) |
                         (v.z ? 4u : 0u) | (v.w ? 8u : 0u);
            bits |= b << (4 * i);
        }
        wsM[bp] = bits;
    }
}

__global__ __launch_bounds__(256, 3) void fused_mlp_v9(
    const float* __restrict__ X, const unsigned* __restrict__ MPK,
    const unsigned short* __restrict__ WFg, const float* __restrict__ BT,
    float* __restrict__ OUT)
{
    __shared__ __align__(16) short sWF[36 * 512];       // 36864 B
    __shared__ __align__(16) short sX[4][2][32 * kXS];  // 36864 B
    __shared__ __align__(16) short sP[4][2][64];        //  1024 B

    const int t = threadIdx.x, w = t >> 6, l = t & 63, c = l & 15, q = l >> 4;
    const size_t bp0 = (size_t)blockIdx.x * 8 + w * 2;

    // ---- stage all 36 W-frags into LDS (wave w: frags 9w..9w+8, 1 KB each;
    // linear dest = wave-uniform base + lane*16, source is lane-linear) ----
    #pragma unroll
    for (int i = 0; i < 9; ++i) {
        int f = w * 9 + i;
        __builtin_amdgcn_global_load_lds(
            (const __attribute__((address_space(1))) void*)(WFg + (size_t)f * 512 + l * 8),
            (__attribute__((address_space(3))) void*)&sWF[f * 512], 16, 0, 0);
    }

    // ---- packed masks: one dword per bp ----
    bool anyv[2];
    float addm[2][8];
    #pragma unroll
    for (int u = 0; u < 2; ++u) {
        unsigned m32 = MPK[bp0 + u];
        anyv[u] = (m32 != 0u);
        // bit i of mb: i<4 -> row 4q+i (mt0); i>=4 -> row 16+4q+(i-4) (mt1)
        unsigned mb = ((m32 >> (4 * q)) & 15u) | (((m32 >> (16 + 4 * q)) & 15u) << 4);
        #pragma unroll
        for (int i = 0; i < 8; ++i)
            addm[u][i] = ((mb >> i) & 1u) ? 0.f : -INFINITY;
    }

    // ---- X loads + immediate bf16 convert ----
    bf16x8 a1f[2][2];
    #pragma unroll
    for (int u = 0; u < 2; ++u)
        #pragma unroll
        for (int mt = 0; mt < 2; ++mt) {
            union { bf16x8 v; unsigned uu[4]; } cv; cv.v = bf16x8{};
            if (q < 2) {
                const float4* p = (const float4*)(X + ((bp0 + u) * 32 + 16 * mt + c) * 16 + q * 8);
                float4 f0 = p[0], f1 = p[1];
                cv.uu[0] = cvtpk(f0.x, f0.y);
                cv.uu[1] = cvtpk(f0.z, f0.w);
                cv.uu[2] = cvtpk(f1.x, f1.y);
                cv.uu[3] = cvtpk(f1.z, f1.w);
            }
            a1f[u][mt] = cv.v;
        }

    __syncthreads();   // staging (and our loads) complete; only barrier

    f32x4 acc[2][2][4];   // [u][mt][nt]

    // ---- layer 1 (K=16 zero-padded to 32): W1 frags 0..3 from LDS ----
    {
        f32x4 bv1 = *(const f32x4*)(BT + c * 4);
        #pragma unroll
        for (int nt = 0; nt < 4; ++nt) {
            bf16x8 wf = *(const bf16x8*)&sWF[nt * 512 + l * 8];
            f32x4 c0 = { bv1[nt], bv1[nt], bv1[nt], bv1[nt] };
            #pragma unroll
            for (int u = 0; u < 2; ++u) {
                acc[u][0][nt] = __builtin_amdgcn_mfma_f32_16x16x32_bf16(a1f[u][0], wf, c0, 0, 0, 0);
                acc[u][1][nt] = __builtin_amdgcn_mfma_f32_16x16x32_bf16(a1f[u][1], wf, c0, 0, 0, 0);
            }
        }
    }

    // ---- epilogue: unmasked lrelu -> LDS bf16, masked pool ----
    auto epilogue = [&](int u, short* xb_, short* pl_) {
        float pool[4];
        #pragma unroll
        for (int nt = 0; nt < 4; ++nt) {
            float pv = -INFINITY;
            #pragma unroll
            for (int mt = 0; mt < 2; ++mt) {
                short* base = &xb_[(16 * mt + 4 * q) * kXS + 16 * nt + c];
                float y0 = lrelu(acc[u][mt][nt][0]);
                float y1 = lrelu(acc[u][mt][nt][1]);
                float y2 = lrelu(acc[u][mt][nt][2]);
                float y3 = lrelu(acc[u][mt][nt][3]);
                pv = fmaxf(pv, y0 + addm[u][mt * 4 + 0]);
                pv = fmaxf(pv, y1 + addm[u][mt * 4 + 1]);
                pv = fmaxf(pv, y2 + addm[u][mt * 4 + 2]);
                pv = fmaxf(pv, y3 + addm[u][mt * 4 + 3]);
                unsigned u01 = cvtpk(y0, y1);
                unsigned u23 = cvtpk(y2, y3);
                base[0 * kXS] = (short)u01;
                base[1 * kXS] = (short)(u01 >> 16);
                base[2 * kXS] = (short)u23;
                base[3 * kXS] = (short)(u23 >> 16);
            }
            pv = fmaxf(pv, __shfl_xor(pv, 16));
            pv = fmaxf(pv, __shfl_xor(pv, 32));
            pool[nt] = anyv[u] ? pv : 0.f;
        }
        float ps = (q & 2) ? ((q & 1) ? pool[3] : pool[2])
                           : ((q & 1) ? pool[1] : pool[0]);
        pl_[16 * q + c] = (short)cvtpk(ps, ps);
    };

    // ---- main rounds: round 0 = layer 2 (frags 4..19, bias BT[1]),
    //      round 1 = layer 3 (frags 20..35, bias BT[2]). Real loop. ----
    #pragma unroll 1
    for (int round = 0; round < 2; ++round) {
        f32x4 bv = *(const f32x4*)(BT + (1 + round) * 64 + c * 4);  // hoisted

        epilogue(0, &sX[w][0][0], &sP[w][0][0]);
        epilogue(1, &sX[w][1][0], &sP[w][1][0]);

        const int fb = 4 + round * 16;
        #pragma unroll
        for (int nt = 0; nt < 4; ++nt) {
            #pragma unroll
            for (int u = 0; u < 2; ++u) {
                acc[u][0][nt] = f32x4{ bv[nt], bv[nt], bv[nt], bv[nt] };
                acc[u][1][nt] = acc[u][0][nt];
            }
        }
        #pragma unroll 1
        for (int ks = 0; ks < 4; ++ks) {
            bf16x8 am[2][2];
            #pragma unroll
            for (int u = 0; u < 2; ++u) {
                const short* xb_ = &sX[w][u][0];
                const short* pl_ = &sP[w][u][0];
                const short* p0 = (ks < 2) ? &xb_[(     c) * kXS + ks * 32 + q * 8]
                                           : &pl_[(ks - 2) * 32 + q * 8];
                const short* p1 = (ks < 2) ? &xb_[(16 + c) * kXS + ks * 32 + q * 8]
                                           : p0;
                am[u][0] = *(const bf16x8*)p0;
                am[u][1] = *(const bf16x8*)p1;
            }
            #pragma unroll
            for (int nt = 0; nt < 4; ++nt) {
                bf16x8 wfv = *(const bf16x8*)&sWF[(fb + nt * 4 + ks) * 512 + l * 8];
                #pragma unroll
                for (int u = 0; u < 2; ++u) {
                    acc[u][0][nt] = __builtin_amdgcn_mfma_f32_16x16x32_bf16(am[u][0], wfv, acc[u][0][nt], 0, 0, 0);
                    acc[u][1][nt] = __builtin_amdgcn_mfma_f32_16x16x32_bf16(am[u][1], wfv, acc[u][1][nt], 0, 0, 0);
                }
            }
        }
    }

    // ---- layer-3 pool == final output, per bp ----
    #pragma unroll
    for (int u = 0; u < 2; ++u) {
        float pool[4];
        #pragma unroll
        for (int nt = 0; nt < 4; ++nt) {
            float pv = -INFINITY;
            #pragma unroll
            for (int mt = 0; mt < 2; ++mt)
                #pragma unroll
                for (int r = 0; r < 4; ++r)
                    pv = fmaxf(pv, lrelu(acc[u][mt][nt][r]) + addm[u][mt * 4 + r]);
            pv = fmaxf(pv, __shfl_xor(pv, 16));
            pv = fmaxf(pv, __shfl_xor(pv, 32));
            pool[nt] = anyv[u] ? pv : 0.f;
        }
        float ps = (q & 2) ? ((q & 1) ? pool[3] : pool[2])
                           : ((q & 1) ? pool[1] : pool[0]);
        OUT[(bp0 + u) * 64 + 16 * q + c] = ps;
    }
}
} // namespace

extern "C" void kernel_launch(void* const* d_in, const int* in_sizes, int n_in,
                              void* d_out, int out_size, void* d_ws, size_t ws_size,
                              hipStream_t stream) {
    (void)in_sizes; (void)n_in; (void)ws_size; (void)out_size;
    const float* X  = (const float*)d_in[0];
    const int*   M  = (const int*)d_in[1];
    const float* W1 = (const float*)d_in[2];
    const float* B1 = (const float*)d_in[3];
    const float* W2 = (const float*)d_in[4];
    const float* B2 = (const float*)d_in[5];
    const float* W3 = (const float*)d_in[6];
    const float* B3 = (const float*)d_in[7];
    float* OUT = (float*)d_out;

    unsigned short* WF = (unsigned short*)d_ws;                    // 36864 B
    float*    BT  = (float*)((char*)d_ws + 36864);                 //   768 B
    unsigned* MPK = (unsigned*)((char*)d_ws + 37632);              // 65536 B

    prep_pack<<<(36 * 64 + 192 + 16384 + 255) / 256, 256, 0, stream>>>(
        W1, W2, W3, B1, B2, B3, M, WF, BT, MPK);
    // 2048 blocks x 4 waves x 2 bp = 16384 bp; two bp per wave
    fused_mlp_v9<<<2048, 256, 0, stream>>>(X, MPK, WF, BT, OUT);
}

// Round 6
// 114.813 us; speedup vs baseline: 1.1405x; 1.1405x over previous
//
#include <hip/hip_runtime.h>
#include <math.h>

// (B,P,V,F,H) = (32,512,32,16,64). Round 10: packed-f16 + 32x32 MFMA +
// transposed swizzled LDS h-layout.
// Model (fits v5-v9): per-wave instruction-stream bound at ~3 waves/SIMD;
// MfmaUtil*dur ~ 7us constant, dur tracks VALU cycles; epilogue = ~75% of
// instructions. So: cut instructions per bp.
//  - f16 activations (pkrtz + v_pk_{add,mul,max}_f16): lrelu/bias/pool at
//    2 vals/op. f16 (10 mant bits) is MORE accurate than prior bf16 (7).
//  - 32x32x16 MFMA: one M-tile (34 MFMA/bp vs 72), pool = 1 shfl.
//    A[m=l&31][k=8*(l>>5)+j], B[k=8*(l>>5)+j][n=l&31],
//    D[row=(r&3)+8*(r>>2)+4*(l>>5)][col=l&31]  (guide, m74/m101-verified).
//  - h stored TRANSPOSED in LDS: addr(m,n) = mt*2048 + (n&7)*32 +
//    ((n>>4)&3)*256 + ((n>>3)&1)*1024 + 2*(m&15), XOR ((n>>4)&3)<<5.
//    Epilogue writes rows m..m+3 at fixed n as ONE ds_write_b64 (8 stores
//    vs 32 scattered b16 + 16 shifts; ~2-way banks via the XOR).
//    layerK A-frag (8 consecutive n at one m): 8 ds_read_b32 at imm
//    offsets 32*(j^ki) (XOR folded at compile time; base bits5..7 clean,
//    no carries) + 4 v_perm half-selects (lane parity).
//    Verified round-trips: h[5][37] -> byte 746 both sides; h[31][24] ->
//    2942 both sides.
//  - zero16 as MFMA C-input for ki==0 (kills 192 acc-init movs); bias via
//    pk_add in epilogue.
//  - reverted v9 regressions: full unroll, W-frags streamed from global.
// Masked rows: stored h is UNMASKED (safe: outputs depend only on pools;
// pools mask via packed -inf addends; mask pattern identical per layer).
namespace {

typedef _Float16 f16x8 __attribute__((ext_vector_type(8)));
typedef _Float16 f16x2 __attribute__((ext_vector_type(2)));
typedef float    f32x16 __attribute__((ext_vector_type(16)));
typedef unsigned int uint;

__device__ __forceinline__ uint pkrtz(float a, float b) {
    return __builtin_bit_cast(uint, __builtin_amdgcn_cvt_pkrtz(a, b));
}
__device__ __forceinline__ uint pk_add(uint a, uint b) {
    uint r; asm("v_pk_add_f16 %0, %1, %2" : "=v"(r) : "v"(a), "v"(b)); return r;
}
__device__ __forceinline__ uint pk_mul(uint a, uint b) {
    uint r; asm("v_pk_mul_f16 %0, %1, %2" : "=v"(r) : "v"(a), "v"(b)); return r;
}
__device__ __forceinline__ uint pk_max(uint a, uint b) {
    uint r; asm("v_pk_max_f16 %0, %1, %2" : "=v"(r) : "v"(a), "v"(b)); return r;
}

// ---- prep: pack W1/W2/W3 as f16 32x32x16 B-frags + per-bp u32 masks ----
// frag f: 0..1 = W1 (ki=0, nt2=f); 2..17 = W2 (ki=(f-2)>>1, nt2=(f-2)&1);
// 18..33 = W3. Lane l of frag f holds W[32*nt2 + (l&31)][16ki + 8*(l>>5)+j].
__global__ void prep_pack(const float* __restrict__ W1, const float* __restrict__ W2,
                          const float* __restrict__ W3, const int* __restrict__ M,
                          unsigned short* __restrict__ wsW, uint* __restrict__ wsM)
{
    int t = blockIdx.x * blockDim.x + threadIdx.x;
    if (t < 34 * 64) {
        int f = t >> 6, l = t & 63, nb = l & 31, kg = l >> 5;
        const float* src; int K, ki, nt2;
        if (f < 2)       { src = W1; K = 16;  ki = 0;           nt2 = f; }
        else if (f < 18) { int g = f - 2;  src = W2; K = 128; ki = g >> 1; nt2 = g & 1; }
        else             { int g = f - 18; src = W3; K = 128; ki = g >> 1; nt2 = g & 1; }
        const float* s = src + (size_t)(32 * nt2 + nb) * K + 16 * ki + 8 * kg;
        uint4 q;
        q.x = pkrtz(s[0], s[1]); q.y = pkrtz(s[2], s[3]);
        q.z = pkrtz(s[4], s[5]); q.w = pkrtz(s[6], s[7]);
        *(uint4*)(wsW + (size_t)f * 512 + l * 8) = q;
    } else if (t < 34 * 64 + 16384) {
        int bp = t - 34 * 64;
        const int4* mp = (const int4*)(M + bp * 32);
        uint bits = 0;
        #pragma unroll
        for (int i = 0; i < 8; ++i) {
            int4 v = mp[i];
            bits |= ((v.x ? 1u : 0u) | (v.y ? 2u : 0u) |
                     (v.z ? 4u : 0u) | (v.w ? 8u : 0u)) << (4 * i);
        }
        wsM[bp] = bits;
    }
}

__global__ __launch_bounds__(256, 3) void fused_mlp_v10(
    const float* __restrict__ X, const uint* __restrict__ MPK,
    const unsigned short* __restrict__ WF,
    const float* __restrict__ B1, const float* __restrict__ B2,
    const float* __restrict__ B3, float* __restrict__ OUT)
{
    __shared__ __align__(16) unsigned char sXb[4][2][4096];  // 32768 B
    __shared__ __align__(16) _Float16 sP[4][2][64];          //  1024 B

    const int t = threadIdx.x, w = t >> 6, l = t & 63;
    const int hb = l >> 5, mtl = (l >> 4) & 1;
    const size_t bp0 = (size_t)blockIdx.x * 8 + w * 2;

    unsigned char* sb[2] = { &sXb[w][0][0], &sXb[w][1][0] };
    _Float16*     pl[2] = { &sP[w][0][0],  &sP[w][1][0]  };

    // write base (byte): rows m..m+3 at col n -> one b64. Lane-const XOR
    // swizzle component folded in; nt2 component via wb1 = (wb0+512)^64.
    uint wb0 = (uint)((l & 7) * 32 + mtl * 256 + ((l >> 3) & 1) * 1024 + hb * 8);
    wb0 ^= (uint)(mtl << 5);
    const uint wb1 = (wb0 + 512u) ^ 64u;
    // read base: + 256*ki + 32*(j^ki) gives dword of (m&~1,m|1) at feature n.
    const uint rb = (uint)(mtl * 2048 + hb * 1024 + ((l & 15) >> 1) * 4);
    const uint sel = (l & 1) ? 0x07060302u : 0x05040100u;  // pick own f16 half
    const uint SL2 = pkrtz(0.01f, 0.01f);

    // ---- masks: packed -inf addends for pool (pairs of rows m,m+1) ----
    bool anyv[2]; uint adm[2][4][2];
    #pragma unroll
    for (int u = 0; u < 2; ++u) {
        uint mk = MPK[bp0 + u];
        anyv[u] = (mk != 0u);
        #pragma unroll
        for (int g = 0; g < 4; ++g) {   // rows 8g+4hb .. +3
            uint nib = (mk >> (8 * g + 4 * hb)) & 15u;
            adm[u][g][0] = (nib & 1u ? 0u : 0xFC00u) | (nib & 2u ? 0u : 0xFC000000u);
            adm[u][g][1] = (nib & 4u ? 0u : 0xFC00u) | (nib & 8u ? 0u : 0xFC000000u);
        }
    }

    // ---- X -> layer-1 A-frags (f16, rtz) ----
    f16x8 a1f[2];
    #pragma unroll
    for (int u = 0; u < 2; ++u) {
        const float4* xp = (const float4*)(X + ((bp0 + u) * 32 + (l & 31)) * 16 + 8 * hb);
        float4 x0 = xp[0], x1 = xp[1];
        uint4 q;
        q.x = pkrtz(x0.x, x0.y); q.y = pkrtz(x0.z, x0.w);
        q.z = pkrtz(x1.x, x1.y); q.w = pkrtz(x1.z, x1.w);
        a1f[u] = __builtin_bit_cast(f16x8, q);
    }

    // persistent zero C-input (16 regs, init once)
    f32x16 zc;
    #pragma unroll
    for (int i = 0; i < 16; ++i) zc[i] = 0.f;

    f32x16 acc[2][2];   // [u][nt2]

    // ---- layer 1 (K=16, one 32x32x16 step, no padding) ----
    {
        const _Float16* wp = (const _Float16*)WF + l * 8;
        f16x8 wf0 = *(const f16x8*)wp;
        f16x8 wf1 = *(const f16x8*)(wp + 512);
        #pragma unroll
        for (int u = 0; u < 2; ++u) {
            acc[u][0] = __builtin_amdgcn_mfma_f32_32x32x16_f16(a1f[u], wf0, zc, 0, 0, 0);
            acc[u][1] = __builtin_amdgcn_mfma_f32_32x32x16_f16(a1f[u], wf1, zc, 0, 0, 0);
        }
    }

    // ---- epilogue: +bias, lrelu, (store h to swizzled LDS), masked pool ----
    auto epi = [&](int u, const float* __restrict__ Bp, bool dostore) {
        unsigned char* sbu = sb[u];
        _Float16* plu = pl[u];
        #pragma unroll
        for (int nt2 = 0; nt2 < 2; ++nt2) {
            float bsc = Bp[32 * nt2 + (l & 31)];
            uint bpk = pkrtz(bsc, bsc);
            uint base = nt2 ? wb1 : wb0;
            uint pp = 0xFC00FC00u;   // (-inf, -inf)
            #pragma unroll
            for (int g = 0; g < 4; ++g) {   // rows m = 8g+4hb .. +3
                uint d01 = pkrtz(acc[u][nt2][4 * g + 0], acc[u][nt2][4 * g + 1]);
                uint d23 = pkrtz(acc[u][nt2][4 * g + 2], acc[u][nt2][4 * g + 3]);
                d01 = pk_add(d01, bpk);  d23 = pk_add(d23, bpk);
                d01 = pk_max(d01, pk_mul(d01, SL2));      // packed lrelu
                d23 = pk_max(d23, pk_mul(d23, SL2));
                if (dostore) {
                    uint2 st; st.x = d01; st.y = d23;
                    *(uint2*)(sbu + base + (g >> 1) * 2048 + (g & 1) * 16) = st;
                }
                pp = pk_max(pp, pk_add(d01, adm[u][g][0]));
                pp = pk_max(pp, pk_add(d23, adm[u][g][1]));
            }
            f16x2 ph = __builtin_bit_cast(f16x2, pp);
            float pv = fmaxf((float)ph[0], (float)ph[1]);
            pv = fmaxf(pv, __shfl_xor(pv, 32));   // merge other hb half
            pv = anyv[u] ? pv : 0.f;
            if (dostore) {
                if (l < 32) plu[32 * nt2 + (l & 31)] = (_Float16)pv;
            } else {
                if (l < 32) OUT[(bp0 + u) * 64 + 32 * nt2 + (l & 31)] = pv;
            }
        }
    };

    // ---- K=128 layer: ki 0..3 from swizzled h, ki 4..7 from pool bcast ----
    auto layerK = [&](int fb) {
        #pragma unroll
        for (int ki = 0; ki < 8; ++ki) {
            const _Float16* wp = (const _Float16*)WF + (size_t)(fb + 2 * ki) * 512 + l * 8;
            f16x8 wf0 = *(const f16x8*)wp;
            f16x8 wf1 = *(const f16x8*)(wp + 512);
            #pragma unroll
            for (int u = 0; u < 2; ++u) {
                f16x8 a;
                if (ki < 4) {
                    const unsigned char* p = sb[u] + rb + 256 * ki;
                    uint F0 = *(const uint*)(p + 32 * (0 ^ ki));
                    uint F1 = *(const uint*)(p + 32 * (1 ^ ki));
                    uint F2 = *(const uint*)(p + 32 * (2 ^ ki));
                    uint F3 = *(const uint*)(p + 32 * (3 ^ ki));
                    uint F4 = *(const uint*)(p + 32 * (4 ^ ki));
                    uint F5 = *(const uint*)(p + 32 * (5 ^ ki));
                    uint F6 = *(const uint*)(p + 32 * (6 ^ ki));
                    uint F7 = *(const uint*)(p + 32 * (7 ^ ki));
                    uint4 q;
                    q.x = __builtin_amdgcn_perm(F1, F0, sel);
                    q.y = __builtin_amdgcn_perm(F3, F2, sel);
                    q.z = __builtin_amdgcn_perm(F5, F4, sel);
                    q.w = __builtin_amdgcn_perm(F7, F6, sel);
                    a = __builtin_bit_cast(f16x8, q);
                } else {
                    a = *(const f16x8*)(pl[u] + 16 * (ki - 4) + 8 * hb);  // bcast
                }
                acc[u][0] = __builtin_amdgcn_mfma_f32_32x32x16_f16(
                    a, wf0, ki == 0 ? zc : acc[u][0], 0, 0, 0);
                acc[u][1] = __builtin_amdgcn_mfma_f32_32x32x16_f16(
                    a, wf1, ki == 0 ? zc : acc[u][1], 0, 0, 0);
            }
        }
    };

    epi(0, B1, true);  epi(1, B1, true);
    layerK(2);
    epi(0, B2, true);  epi(1, B2, true);
    layerK(18);
    epi(0, B3, false); epi(1, B3, false);   // layer-3 pool == final output
}
} // namespace

extern "C" void kernel_launch(void* const* d_in, const int* in_sizes, int n_in,
                              void* d_out, int out_size, void* d_ws, size_t ws_size,
                              hipStream_t stream) {
    (void)in_sizes; (void)n_in; (void)ws_size; (void)out_size;
    const float* X  = (const float*)d_in[0];
    const int*   M  = (const int*)d_in[1];
    const float* W1 = (const float*)d_in[2];
    const float* B1 = (const float*)d_in[3];
    const float* W2 = (const float*)d_in[4];
    const float* B2 = (const float*)d_in[5];
    const float* W3 = (const float*)d_in[6];
    const float* B3 = (const float*)d_in[7];
    float* OUT = (float*)d_out;

    unsigned short* WF  = (unsigned short*)d_ws;              // 34816 B
    uint*           MPK = (uint*)((char*)d_ws + 34816);       // 65536 B

    prep_pack<<<(34 * 64 + 16384 + 255) / 256, 256, 0, stream>>>(W1, W2, W3, M, WF, MPK);
    // 2048 blocks x 4 waves x 2 bp = 16384 bp; two bp per wave
    fused_mlp_v10<<<2048, 256, 0, stream>>>(X, MPK, WF, B1, B2, B3, OUT);
}

// Round 7
// 114.603 us; speedup vs baseline: 1.1425x; 1.0018x over previous
//
#include <hip/hip_runtime.h>
#include <math.h>

// (B,P,V,F,H) = (32,512,32,16,64). Round 11: SKEWED bp-pipeline + bank fix.
// Model (fits v5-v10): per-CU pipe budgets SUM instead of overlapping
// (MFMA 7 + VALU 13 + DS 11 + VMEM 8 ~= 39 ~= 46 measured): all waves march
// through the same phase sequence in lockstep, so each phase queues every
// wave on one pipe while the others idle. Single-pipe fixes (occupancy v6,
// spill v7, VMEM v8, VALU v10) each moved only their own term.
// Fix 1 (SKEW): manually interleave u1's epilogue (VALU) into u0's layerK
// (MFMA+DS+VMEM), one epi-slice per ki step; bps are independent -> legal;
// intra-wave -> occupancy-independent. W-frags now loaded per-u (64 vs 32
// dwordx4/wave) — hidden under the overlapped epilogue VALU.
// Fix 2 (banks, v10 had 5.24M conflict-cycles = 4-way reads): extend the
// swizzle: swz(a) = a ^ ((a>>8)&3)<<5 [v10] ^ ((a>>10)&1)<<4 ^ ((a>>11)&1)<<5.
// Folded at zero per-access cost: reads use parity bases pA/pB (rbA, rbA^32)
// + compile-time offsets 256ki+32*((j^ki)&~1); writes XOR compile-time
// ((g&1)<<4)^((g>>1)<<5) into the base. Round-trips verified: (m=5,n=37)
// -> 746 both sides; (m=20,n=13) -> 3224 write path == 3224 read path.
// Reads become conflict-free (32 banks), writes ~2-way.
// Layout/numerics otherwise identical to v10 (passed, absmax 0.0078):
// f16 acts, 32x32x16 MFMA, packed epilogue, addm pool masking, pools-only
// output. MFMA: A[m=l&31][k=8*(l>>5)+j], B[k][n=l&31],
// D[row=(r&3)+8*(r>>2)+4*(l>>5)][col=l&31].
namespace {

typedef _Float16 f16x8 __attribute__((ext_vector_type(8)));
typedef _Float16 f16x2 __attribute__((ext_vector_type(2)));
typedef float    f32x16 __attribute__((ext_vector_type(16)));
typedef unsigned int uint;

__device__ __forceinline__ uint pkrtz(float a, float b) {
    return __builtin_bit_cast(uint, __builtin_amdgcn_cvt_pkrtz(a, b));
}
__device__ __forceinline__ uint pk_add(uint a, uint b) {
    uint r; asm("v_pk_add_f16 %0, %1, %2" : "=v"(r) : "v"(a), "v"(b)); return r;
}
__device__ __forceinline__ uint pk_mul(uint a, uint b) {
    uint r; asm("v_pk_mul_f16 %0, %1, %2" : "=v"(r) : "v"(a), "v"(b)); return r;
}
__device__ __forceinline__ uint pk_max(uint a, uint b) {
    uint r; asm("v_pk_max_f16 %0, %1, %2" : "=v"(r) : "v"(a), "v"(b)); return r;
}

// ---- prep: pack W1/W2/W3 as f16 32x32x16 B-frags + per-bp u32 masks ----
// frag f: 0..1 = W1 (ki=0, nt2=f); 2..17 = W2 (ki=(f-2)>>1, nt2=(f-2)&1);
// 18..33 = W3. Lane l of frag f holds W[32*nt2 + (l&31)][16ki + 8*(l>>5)+j].
__global__ void prep_pack(const float* __restrict__ W1, const float* __restrict__ W2,
                          const float* __restrict__ W3, const int* __restrict__ M,
                          unsigned short* __restrict__ wsW, uint* __restrict__ wsM)
{
    int t = blockIdx.x * blockDim.x + threadIdx.x;
    if (t < 34 * 64) {
        int f = t >> 6, l = t & 63, nb = l & 31, kg = l >> 5;
        const float* src; int K, ki, nt2;
        if (f < 2)       { src = W1; K = 16;  ki = 0;           nt2 = f; }
        else if (f < 18) { int g = f - 2;  src = W2; K = 128; ki = g >> 1; nt2 = g & 1; }
        else             { int g = f - 18; src = W3; K = 128; ki = g >> 1; nt2 = g & 1; }
        const float* s = src + (size_t)(32 * nt2 + nb) * K + 16 * ki + 8 * kg;
        uint4 q;
        q.x = pkrtz(s[0], s[1]); q.y = pkrtz(s[2], s[3]);
        q.z = pkrtz(s[4], s[5]); q.w = pkrtz(s[6], s[7]);
        *(uint4*)(wsW + (size_t)f * 512 + l * 8) = q;
    } else if (t < 34 * 64 + 16384) {
        int bp = t - 34 * 64;
        const int4* mp = (const int4*)(M + bp * 32);
        uint bits = 0;
        #pragma unroll
        for (int i = 0; i < 8; ++i) {
            int4 v = mp[i];
            bits |= ((v.x ? 1u : 0u) | (v.y ? 2u : 0u) |
                     (v.z ? 4u : 0u) | (v.w ? 8u : 0u)) << (4 * i);
        }
        wsM[bp] = bits;
    }
}

__global__ __launch_bounds__(256, 3) void fused_mlp_v11(
    const float* __restrict__ X, const uint* __restrict__ MPK,
    const unsigned short* __restrict__ WF,
    const float* __restrict__ B1, const float* __restrict__ B2,
    const float* __restrict__ B3, float* __restrict__ OUT)
{
    __shared__ __align__(16) unsigned char sXb[4][2][4096];  // 32768 B
    __shared__ __align__(16) _Float16 sP[4][2][64];          //  1024 B

    const int t = threadIdx.x, w = t >> 6, l = t & 63;
    const int hb = l >> 5, mtl = (l >> 4) & 1, l3 = (l >> 3) & 1;
    const size_t bp0 = (size_t)blockIdx.x * 8 + w * 2;

    unsigned char* sb[2] = { &sXb[w][0][0], &sXb[w][1][0] };
    _Float16*     pl[2] = { &sP[w][0][0],  &sP[w][1][0]  };

    // write base: rows m..m+3 at col n -> one b64; full swizzle folded.
    uint wb0 = (uint)((l & 7) * 32 + mtl * 256 + l3 * 1024 + hb * 8);
    wb0 ^= (uint)((mtl << 5) ^ (l3 << 4));
    const uint wb1 = (wb0 + 512u) ^ 64u;
    // read bases: parity pair handles the ((a>>11)&1)<<5 term carry-free.
    uint rbA = (uint)(mtl * 2048 + hb * 1024 + ((l & 15) >> 1) * 4);
    rbA ^= (uint)((hb << 4) ^ (mtl << 5));
    const uint rbB = rbA ^ 32u;
    const uint sel = (l & 1) ? 0x07060302u : 0x05040100u;  // own f16 half
    const uint SL2 = pkrtz(0.01f, 0.01f);

    // ---- masks: packed -inf addends for pool (pairs of rows m,m+1) ----
    bool anyv[2]; uint adm[2][4][2];
    #pragma unroll
    for (int u = 0; u < 2; ++u) {
        uint mk = MPK[bp0 + u];
        anyv[u] = (mk != 0u);
        #pragma unroll
        for (int g = 0; g < 4; ++g) {   // rows 8g+4hb .. +3
            uint nib = (mk >> (8 * g + 4 * hb)) & 15u;
            adm[u][g][0] = (nib & 1u ? 0u : 0xFC00u) | (nib & 2u ? 0u : 0xFC000000u);
            adm[u][g][1] = (nib & 4u ? 0u : 0xFC00u) | (nib & 8u ? 0u : 0xFC000000u);
        }
    }

    // ---- X -> layer-1 A-frags (f16, rtz) ----
    f16x8 a1f[2];
    #pragma unroll
    for (int u = 0; u < 2; ++u) {
        const float4* xp = (const float4*)(X + ((bp0 + u) * 32 + (l & 31)) * 16 + 8 * hb);
        float4 x0 = xp[0], x1 = xp[1];
        uint4 q;
        q.x = pkrtz(x0.x, x0.y); q.y = pkrtz(x0.z, x0.w);
        q.z = pkrtz(x1.x, x1.y); q.w = pkrtz(x1.z, x1.w);
        a1f[u] = __builtin_bit_cast(f16x8, q);
    }

    f32x16 zc;
    #pragma unroll
    for (int i = 0; i < 16; ++i) zc[i] = 0.f;

    f32x16 acc[2][2];   // [u][nt2]

    // ---- layer 1 (K=16, one 32x32x16 step) ----
    {
        const _Float16* wp = (const _Float16*)WF + l * 8;
        f16x8 wf0 = *(const f16x8*)wp;
        f16x8 wf1 = *(const f16x8*)(wp + 512);
        acc[0][0] = __builtin_amdgcn_mfma_f32_32x32x16_f16(a1f[0], wf0, zc, 0, 0, 0);
        acc[0][1] = __builtin_amdgcn_mfma_f32_32x32x16_f16(a1f[0], wf1, zc, 0, 0, 0);
        acc[1][0] = __builtin_amdgcn_mfma_f32_32x32x16_f16(a1f[1], wf0, zc, 0, 0, 0);
        acc[1][1] = __builtin_amdgcn_mfma_f32_32x32x16_f16(a1f[1], wf1, zc, 0, 0, 0);
    }

    // ---- one epilogue slice (nt2=s>>2, g=s&3): +bias, lrelu, store, pool ----
    auto epi_slice = [&](int ue, int s, uint bpk0, uint bpk1,
                         uint& pp0, uint& pp1, bool dostore) {
        const int nt2 = s >> 2, g = s & 3;
        const f32x16& A = acc[ue][nt2];
        uint bpk = nt2 ? bpk1 : bpk0;
        uint d01 = pk_add(pkrtz(A[4 * g + 0], A[4 * g + 1]), bpk);
        uint d23 = pk_add(pkrtz(A[4 * g + 2], A[4 * g + 3]), bpk);
        d01 = pk_max(d01, pk_mul(d01, SL2));      // packed lrelu
        d23 = pk_max(d23, pk_mul(d23, SL2));
        if (dostore) {
            uint wba = ((nt2 ? wb1 : wb0)
                        ^ (uint)(((g & 1) << 4) ^ ((g >> 1) << 5)))
                       + (uint)((g >> 1) * 2048);
            uint2 st; st.x = d01; st.y = d23;
            *(uint2*)(sb[ue] + wba) = st;
        }
        uint& pp = nt2 ? pp1 : pp0;
        pp = pk_max(pp, pk_add(d01, adm[ue][g][0]));
        pp = pk_max(pp, pk_add(d23, adm[ue][g][1]));
    };

    auto epi_fin = [&](int ue, uint pp0, uint pp1, bool dostore) {
        #pragma unroll
        for (int nt2 = 0; nt2 < 2; ++nt2) {
            f16x2 ph = __builtin_bit_cast(f16x2, nt2 ? pp1 : pp0);
            float pv = fmaxf((float)ph[0], (float)ph[1]);
            pv = fmaxf(pv, __shfl_xor(pv, 32));   // merge other hb half
            pv = anyv[ue] ? pv : 0.f;
            if (dostore) {
                if (l < 32) pl[ue][32 * nt2 + (l & 31)] = (_Float16)pv;
            } else {
                if (l < 32) OUT[(bp0 + ue) * 64 + 32 * nt2 + (l & 31)] = pv;
            }
        }
    };

    auto epi_full = [&](int ue, const float* __restrict__ Bp, bool dostore) {
        uint pp0 = 0xFC00FC00u, pp1 = 0xFC00FC00u;
        float b0 = Bp[l & 31], b1 = Bp[32 + (l & 31)];
        uint bpk0 = pkrtz(b0, b0), bpk1 = pkrtz(b1, b1);
        #pragma unroll
        for (int s = 0; s < 8; ++s)
            epi_slice(ue, s, bpk0, bpk1, pp0, pp1, dostore);
        epi_fin(ue, pp0, pp1, dostore);
    };

    // ---- skewed step: layerK of uk INTERLEAVED with epilogue of ue ----
    auto fused_step = [&](int uk, int fb, int ue, const float* __restrict__ Bp,
                          bool store_epi) {
        uint pp0 = 0xFC00FC00u, pp1 = 0xFC00FC00u;
        float b0 = Bp[l & 31], b1 = Bp[32 + (l & 31)];
        uint bpk0 = pkrtz(b0, b0), bpk1 = pkrtz(b1, b1);
        const unsigned char* pA = sb[uk] + rbA;
        const unsigned char* pB = sb[uk] + rbB;
        f32x16 na0, na1;
        #pragma unroll
        for (int ki = 0; ki < 8; ++ki) {
            const _Float16* wp = (const _Float16*)WF + (size_t)(fb + 2 * ki) * 512 + l * 8;
            f16x8 wf0 = *(const f16x8*)wp;
            f16x8 wf1 = *(const f16x8*)(wp + 512);
            f16x8 a;
            if (ki < 4) {
                uint F[8];
                #pragma unroll
                for (int j = 0; j < 8; ++j) {
                    const int e = j ^ ki;
                    const uint off = (uint)(256 * ki + 32 * (e & ~1));
                    F[j] = *(const uint*)(((e & 1) ? pB : pA) + off);
                }
                uint4 q;
                q.x = __builtin_amdgcn_perm(F[1], F[0], sel);
                q.y = __builtin_amdgcn_perm(F[3], F[2], sel);
                q.z = __builtin_amdgcn_perm(F[5], F[4], sel);
                q.w = __builtin_amdgcn_perm(F[7], F[6], sel);
                a = __builtin_bit_cast(f16x8, q);
            } else {
                a = *(const f16x8*)(pl[uk] + 16 * (ki - 4) + 8 * hb);  // bcast
            }
            na0 = __builtin_amdgcn_mfma_f32_32x32x16_f16(a, wf0, ki ? na0 : zc, 0, 0, 0);
            na1 = __builtin_amdgcn_mfma_f32_32x32x16_f16(a, wf1, ki ? na1 : zc, 0, 0, 0);
            // one slice of ue's epilogue per ki: VALU overlaps MFMA/DS/VMEM
            epi_slice(ue, ki, bpk0, bpk1, pp0, pp1, store_epi);
        }
        epi_fin(ue, pp0, pp1, store_epi);
        acc[uk][0] = na0; acc[uk][1] = na1;
    };

    // ---- skewed chain (uk != ue always; LDS buffers disjoint) ----
    epi_full(0, B1, true);                 // stage u0-L1
    fused_step(0, 2,  1, B1, true);        // u0 layerK-L2 || stage u1-L1
    fused_step(1, 2,  0, B2, true);        // u1 layerK-L2 || stage u0-L2
    fused_step(0, 18, 1, B2, true);        // u0 layerK-L3 || stage u1-L2
    fused_step(1, 18, 0, B3, false);       // u1 layerK-L3 || final-out u0
    epi_full(1, B3, false);                // final-out u1
}
} // namespace

extern "C" void kernel_launch(void* const* d_in, const int* in_sizes, int n_in,
                              void* d_out, int out_size, void* d_ws, size_t ws_size,
                              hipStream_t stream) {
    (void)in_sizes; (void)n_in; (void)ws_size; (void)out_size;
    const float* X  = (const float*)d_in[0];
    const int*   M  = (const int*)d_in[1];
    const float* W1 = (const float*)d_in[2];
    const float* B1 = (const float*)d_in[3];
    const float* W2 = (const float*)d_in[4];
    const float* B2 = (const float*)d_in[5];
    const float* W3 = (const float*)d_in[6];
    const float* B3 = (const float*)d_in[7];
    float* OUT = (float*)d_out;

    unsigned short* WF  = (unsigned short*)d_ws;              // 34816 B
    uint*           MPK = (uint*)((char*)d_ws + 34816);       // 65536 B

    prep_pack<<<(34 * 64 + 16384 + 255) / 256, 256, 0, stream>>>(W1, W2, W3, M, WF, MPK);
    // 2048 blocks x 4 waves x 2 bp = 16384 bp; two bp per wave
    fused_mlp_v11<<<2048, 256, 0, stream>>>(X, MPK, WF, B1, B2, B3, OUT);
}